// Round 2
// baseline (184.482 us; speedup 1.0000x reference)
//
#include <hip/hip_runtime.h>

// STDP delta_w on MI355X, bf16-MFMA formulation (2-dispatch).
//   term1: dW1[o,p] = sum_k O[k,o]*TP[k,p], K = T*B = 1024  -> bf16 MFMA GEMM
//   term2: -coef[o]*W[o,p], coef[o] = sum_k O[k,o]*PO[k,o]  -> fp32 epilogue
//
// R8: GEMM rebuilt as counted-vmcnt pipeline (T3+T4+T5 per guide §5.5):
//   BM=256 x BN=128, BK=64, 8 waves (512 thr), 3-buffer LDS (144 KB),
//   depth-2 prefetch -> boundary waits are s_waitcnt vmcnt(10/6) (never 0
//   in steady state), raw s_barrier, setprio around MFMA clusters,
//   XOR chunk swizzle (verified R6 scheme, 0 bank conflicts),
//   W half-prefetched into regs during main loop, XCD-bijective swizzle.
// Converter identical to R4 (verified correct).
//
// ws: AT bf16 [4096][1024] (8MB) | BT bf16 [4096][1024] (8MB) | coef f32[4096]

#define T_STEPS 64
#define B_SZ    16
#define PRE     4096
#define POST    4096
#define K_TOT   1024

typedef __attribute__((ext_vector_type(8))) unsigned short ushort8;
typedef __attribute__((ext_vector_type(8))) __bf16 bf16x8;
typedef __attribute__((ext_vector_type(4))) float floatx4;

__device__ __forceinline__ unsigned short f2bf(float f) {
    unsigned int u = __float_as_uint(f);
    u += 0x7fff + ((u >> 16) & 1);          // round-to-nearest-even
    return (unsigned short)(u >> 16);
}

__device__ __forceinline__ void glds16(const void* g, void* l) {
    __builtin_amdgcn_global_load_lds((const __attribute__((address_space(1))) void*)g,
                                     (__attribute__((address_space(3))) void*)l,
                                     16, 0, 0);
}

// ---------------------------------------------------------------------------
// Converter: grid = 256 blocks (matrix = blk>>7, p-chunk = blk&127), 256 thr.
// (verbatim R4 — passed)
__global__ __launch_bounds__(256) void trace_convert(
        const float* __restrict__ in_spikes,
        const float* __restrict__ out_spikes,
        unsigned short* __restrict__ AT,
        unsigned short* __restrict__ BT,
        float* __restrict__ coef) {
    __shared__ float ldsf[4096];             // [8 t][16 b][32 p] fp32, 16 KB
    __shared__ unsigned short ot[128 * 34];  // [128 k][32 p + 2 pad], 8.5 KB
    __shared__ float cbuf[8][33];
    const int tid  = threadIdx.x;
    const int wave = tid >> 6;
    const int lane = tid & 63;
    const bool isA = blockIdx.x >= 128;
    const int p0 = (blockIdx.x & 127) * 32;
    const float* src = isA ? out_spikes : in_spikes;
    unsigned short* dst = isA ? AT : BT;

    const int bA = tid >> 5;                 // chains (bA, p) and (bA+8, p)
    const int pA = tid & 31;

    float st0 = 0.f, st1 = 0.f, c0 = 0.f, c1 = 0.f;

    for (int tc = 0; tc < 8; ++tc) {
        const int T0 = tc * 8;
        // ---- stage 16 b x 8 t x 32 p fp32 into LDS (4 glds x16B per wave)
        #pragma unroll
        for (int i = 0; i < 4; ++i) {
            const int q  = (wave * 4 + i) * 64 + lane;  // float-quad id 0..1023
            const int p  = (q & 7) * 4;
            const int b  = (q >> 3) & 15;
            const int tl = q >> 7;
            const float* g = src + ((size_t)((T0 + tl) * 16 + b)) * 4096 + p0 + p;
            glds16(g, (char*)ldsf + (size_t)(wave * 4 + i) * 1024);
        }
        __syncthreads();                     // drains vmcnt

        // ---- recurrence: 8 t-steps, 2 chains per thread
        #pragma unroll
        for (int tl = 0; tl < 8; ++tl) {
            const float x0 = ldsf[tl * 512 + bA * 32 + pA];
            const float x1 = ldsf[tl * 512 + (bA + 8) * 32 + pA];
            if (isA) {
                st0 = 0.5f * st0 + x0; c0 += x0 * st0;   // po update, then o*po
                st1 = 0.5f * st1 + x1; c1 += x1 * st1;
                ot[(tl * 16 + bA)     * 34 + pA] = f2bf(x0);
                ot[(tl * 16 + bA + 8) * 34 + pA] = f2bf(x1);
            } else {
                st0 = fminf(fmaxf(0.5f * st0 + x0, 0.f), 1.f);
                st1 = fminf(fmaxf(0.5f * st1 + x1, 0.f), 1.f);
                ot[(tl * 16 + bA)     * 34 + pA] = f2bf(st0);
                ot[(tl * 16 + bA + 8) * 34 + pA] = f2bf(st1);
            }
        }
        __syncthreads();

        // ---- flush: 128 contiguous k per p-row, 16-B vector stores
        const int pf = tid >> 3;             // 0..31
        const int c8 = tid & 7;
        #pragma unroll
        for (int i = 0; i < 2; ++i) {
            const int ch = c8 + i * 8;       // 16-B chunk 0..15
            ushort8 v;
            #pragma unroll
            for (int s = 0; s < 8; ++s) v[s] = ot[(ch * 8 + s) * 34 + pf];
            *(ushort8*)&dst[(size_t)(p0 + pf) * K_TOT + T0 * 16 + ch * 8] = v;
        }
    }

    if (isA) {
        cbuf[bA][pA] = c0 + c1;              // partial over b in {bA, bA+8}
        __syncthreads();
        if (tid < 32) {
            float s = 0.f;
            #pragma unroll
            for (int r = 0; r < 8; ++r) s += cbuf[r][tid];
            coef[p0 + tid] = s;
        }
    }
}

// ---------------------------------------------------------------------------
// Counted-vmcnt pipelined GEMM.
//   Tile: BM=256 (POST rows) x BN=128 (PRE cols), BK=64, 16 K-tiles.
//   8 waves as 4M x 2N; per wave 4x4 16x16 frags (64x64 output), 32 MFMA/tile.
//   LDS: 3 buffers x (A 32KB + B 16KB) = 144 KB; prefetch depth 2 tiles.
//   Boundary t: wait vmcnt(10) [t<8: 6 glds of S(t+2) + 4 W-loads in flight]
//               or vmcnt(6) [8<=t<14] or vmcnt(0) [t=14 tail]; raw s_barrier.
//   Safety: each wave's counted wait covers its OWN S(t+1) glds before the
//   barrier (glds completion is only tracked by the issuing wave) -> data
//   visible to all waves after barrier. S(t+2) targets buf (t+2)%3, never
//   the buffer being read (t%3) or landing (t+1)%3.
#define BK 64
#define NTILES (K_TOT / BK)

__global__ __launch_bounds__(512, 2) void stdp_gemm_mfma(
        const unsigned short* __restrict__ AT,   // [POST][K] bf16 bits
        const unsigned short* __restrict__ BT,   // [PRE][K]  bf16 bits
        const float* __restrict__ W,             // [POST][PRE]
        const float* __restrict__ coef,          // [POST]
        float* __restrict__ Cout) {              // [POST][PRE]
    __shared__ __align__(16) char lds[3][49152];  // per buf: A @0 (32KB), B @32768 (16KB)

    const int tid  = threadIdx.x;
    const int lane = tid & 63;
    const int wave = tid >> 6;

    // XCD-bijective swizzle: 512 blocks, 64 per XCD (contiguous flat chunk).
    const int bid = blockIdx.x;
    const int f   = (bid & 7) * 64 + (bid >> 3);
    const int m0  = (f >> 5) * 256;              // 16 m-tiles
    const int n0  = (f & 31) * 128;              // 32 n-tiles

    const int wm = (wave >> 1) * 64;             // 4 M-groups
    const int wn = (wave & 1) * 64;              // 2 N-groups
    const int rm = lane & 15;                    // fragment row
    const int q  = lane >> 4;                    // k-quad
    const int sw = rm & 7;                       // read-side swizzle

    floatx4 acc[4][4];
    #pragma unroll
    for (int i = 0; i < 4; ++i)
        #pragma unroll
        for (int j = 0; j < 4; ++j)
            acc[i][j] = (floatx4){0.f, 0.f, 0.f, 0.f};
    float wr[8][4];                              // W prefetch: mi 0..1 x r 0..3

    // Staging map: thread -> row srow=tid>>3 (+64 per instr), slot tid&7,
    // receiving global chunk (tid&7)^(row&7). Row = 128 B = 8 chunks.
    const int srow = tid >> 3;                   // 0..63
    const int qg   = (tid & 7) ^ (srow & 7);
    const unsigned short* ga = &AT[(size_t)(m0 + srow) * K_TOT + qg * 8];
    const unsigned short* gb = &BT[(size_t)(n0 + srow) * K_TOT + qg * 8];
    const int colp = n0 + wn + rm;

    auto STAGE = [&](int t) {                    // 6 glds: A rows 0..255, B rows 0..127
        char* base = (char*)&lds[t % 3][0] + wave * 1024;
        const unsigned short* gaT = ga + t * BK;
        const unsigned short* gbT = gb + t * BK;
        #pragma unroll
        for (int i = 0; i < 4; ++i)
            glds16(gaT + (size_t)i * 64 * K_TOT, base + i * 8192);
        #pragma unroll
        for (int i = 0; i < 2; ++i)
            glds16(gbT + (size_t)i * 64 * K_TOT, base + 32768 + i * 8192);
    };

    // Prologue: tiles 0,1 staged; wait tile0 resident (tile1's 6 in flight).
    STAGE(0);
    asm volatile("" ::: "memory");               // keep issue-group order
    STAGE(1);
    asm volatile("s_waitcnt vmcnt(6)" ::: "memory");
    __builtin_amdgcn_s_barrier();
    __builtin_amdgcn_sched_barrier(0);

    #pragma unroll
    for (int t = 0; t < NTILES; ++t) {
        if (t + 2 < NTILES) STAGE(t + 2);
        if (t < 8) {                             // W prefetch, 4 scalar loads
            const int o = m0 + wm + q * 4 + (t >> 2) * 16 + (t & 3);
            const float* wrow = &W[(size_t)o * PRE + colp];
            #pragma unroll
            for (int ni = 0; ni < 4; ++ni) wr[t][ni] = wrow[ni * 16];
        }
        const char* Ab = (const char*)&lds[t % 3][0];
        const char* Bb = Ab + 32768;
        #pragma unroll
        for (int h = 0; h < 2; ++h) {            // two 32-k halves
            bf16x8 af[4], bv[4];
            #pragma unroll
            for (int i = 0; i < 4; ++i) {
                const int ks = ((h * 4 + q) ^ sw) * 16;
                af[i] = *(const bf16x8*)(Ab + (wm + i * 16 + rm) * 128 + ks);
                bv[i] = *(const bf16x8*)(Bb + (wn + i * 16 + rm) * 128 + ks);
            }
            __builtin_amdgcn_s_setprio(1);
            #pragma unroll
            for (int mi = 0; mi < 4; ++mi)
                #pragma unroll
                for (int ni = 0; ni < 4; ++ni)
                    acc[mi][ni] = __builtin_amdgcn_mfma_f32_16x16x32_bf16(
                        af[mi], bv[ni], acc[mi][ni], 0, 0, 0);
            __builtin_amdgcn_s_setprio(0);
        }
        if (t < NTILES - 1) {                    // boundary: counted wait + barrier
            if (t < 8)       asm volatile("s_waitcnt vmcnt(10)" ::: "memory");
            else if (t < 14) asm volatile("s_waitcnt vmcnt(6)"  ::: "memory");
            else             asm volatile("s_waitcnt vmcnt(0)"  ::: "memory");
            __builtin_amdgcn_s_barrier();
            __builtin_amdgcn_sched_barrier(0);
        }
    }

    // Epilogue: C = acc - coef[o]*W. C/D layout: col=lane&15, row=quad*4+reg.
    #pragma unroll
    for (int mi = 0; mi < 4; ++mi) {
        #pragma unroll
        for (int r = 0; r < 4; ++r) {
            const int o = m0 + wm + q * 4 + mi * 16 + r;
            const float cf = coef[o];
            const float* wrow = &W[(size_t)o * PRE + colp];
            float* crow = &Cout[(size_t)o * PRE + colp];
            #pragma unroll
            for (int ni = 0; ni < 4; ++ni) {
                const float wv = (mi < 2) ? wr[mi * 4 + r][ni] : wrow[ni * 16];
                crow[ni * 16] = acc[mi][ni][r] - cf * wv;
            }
        }
    }
}

// ---------------------------------------------------------------------------
extern "C" void kernel_launch(void* const* d_in, const int* in_sizes, int n_in,
                              void* d_out, int out_size, void* d_ws, size_t ws_size,
                              hipStream_t stream) {
    const float* in_spikes  = (const float*)d_in[0];
    const float* out_spikes = (const float*)d_in[1];
    const float* weight     = (const float*)d_in[2];
    float* out = (float*)d_out;

    unsigned short* AT = (unsigned short*)d_ws;                 // 8 MB
    unsigned short* BT = AT + (size_t)POST * K_TOT;             // 8 MB
    float* coef = (float*)(BT + (size_t)PRE * K_TOT);           // 16 KB

    trace_convert<<<256, 256, 0, stream>>>(in_spikes, out_spikes, AT, BT, coef);

    stdp_gemm_mfma<<<512, 512, 0, stream>>>(AT, BT, weight, coef, out);
}

// Round 3
// 180.810 us; speedup vs baseline: 1.0203x; 1.0203x over previous
//
#include <hip/hip_runtime.h>

// STDP delta_w on MI355X, bf16-MFMA formulation (2-dispatch).
//   term1: dW1[o,p] = sum_k O[k,o]*TP[k,p], K = T*B = 1024  -> bf16 MFMA GEMM
//   term2: -coef[o]*W[o,p], coef[o] = sum_k O[k,o]*PO[k,o]  -> fp32 epilogue
//
// R9: GEMM ported to the m201 8-phase template (T3+T4+T5):
//   BM=BN=256, BK=64, 8 waves (2M x 4N), per-wave C = 128x64 (acc[8][4]).
//   LDS 128 KB: 2 dbuf x {A,B} x 2 k-halves x [256 rows][32 k][2B] (16 KB half-tiles).
//   Per iter (2 K-tiles): 8 phases, each {ds_read 4-8 x b128 | stage 1 half-tile
//   (2 glds) | counted vmcnt at ph4/ph8 only | s_barrier | setprio(1) 16 MFMA
//   setprio(0) | s_barrier}. Stage ledger (iter i, tiles 2i,2i+1 in buf0/buf1):
//     ph1: A(2i+1)k1 -> buf1.k1 (dead since ph8 of i-1)   [skip at i=0: prologue]
//     ph2: B(2i+1)k1 -> buf1.k1
//     ph3: A(2i+2)k0 -> buf0.k0 (dead after ph2)
//     ph4: B(2i+2)k0; wait vmcnt(4) (i<7) / vmcnt(0) (i=7) -> publishes buf1
//     ph5: A(2i+2)k1 -> buf0.k1 (dead after ph4)
//     ph6: B(2i+2)k1
//     ph7: A(2i+3)k0 -> buf1.k0 (dead after ph6)
//     ph8: B(2i+3)k0; wait vmcnt(4) -> publishes buf0 for iter i+1
//   Prologue stages tiles 0,1 (16 glds), vmcnt(8) covers tile 0.
//   Swizzle: LDS row = 64B = 4 chunks; store slot s holds global chunk
//   s ^ ((row>>1)&3) (inverse-perm on global src, linear glds dest);
//   read slot = q ^ ((row>>1)&3) -> 2-way per quarter-wave = conflict-free.
// Converter identical to R4 (verified correct).
//
// ws: AT bf16 [4096][1024] (8MB) | BT bf16 [4096][1024] (8MB) | coef f32[4096]

#define T_STEPS 64
#define B_SZ    16
#define PRE     4096
#define POST    4096
#define K_TOT   1024

typedef __attribute__((ext_vector_type(8))) unsigned short ushort8;
typedef __attribute__((ext_vector_type(8))) __bf16 bf16x8;
typedef __attribute__((ext_vector_type(4))) float floatx4;

__device__ __forceinline__ unsigned short f2bf(float f) {
    unsigned int u = __float_as_uint(f);
    u += 0x7fff + ((u >> 16) & 1);          // round-to-nearest-even
    return (unsigned short)(u >> 16);
}

__device__ __forceinline__ void glds16(const void* g, void* l) {
    __builtin_amdgcn_global_load_lds((const __attribute__((address_space(1))) void*)g,
                                     (__attribute__((address_space(3))) void*)l,
                                     16, 0, 0);
}

// ---------------------------------------------------------------------------
// Converter: grid = 256 blocks (matrix = blk>>7, p-chunk = blk&127), 256 thr.
// (verbatim R4 — passed)
__global__ __launch_bounds__(256) void trace_convert(
        const float* __restrict__ in_spikes,
        const float* __restrict__ out_spikes,
        unsigned short* __restrict__ AT,
        unsigned short* __restrict__ BT,
        float* __restrict__ coef) {
    __shared__ float ldsf[4096];             // [8 t][16 b][32 p] fp32, 16 KB
    __shared__ unsigned short ot[128 * 34];  // [128 k][32 p + 2 pad], 8.5 KB
    __shared__ float cbuf[8][33];
    const int tid  = threadIdx.x;
    const int wave = tid >> 6;
    const int lane = tid & 63;
    const bool isA = blockIdx.x >= 128;
    const int p0 = (blockIdx.x & 127) * 32;
    const float* src = isA ? out_spikes : in_spikes;
    unsigned short* dst = isA ? AT : BT;

    const int bA = tid >> 5;                 // chains (bA, p) and (bA+8, p)
    const int pA = tid & 31;

    float st0 = 0.f, st1 = 0.f, c0 = 0.f, c1 = 0.f;

    for (int tc = 0; tc < 8; ++tc) {
        const int T0 = tc * 8;
        // ---- stage 16 b x 8 t x 32 p fp32 into LDS (4 glds x16B per wave)
        #pragma unroll
        for (int i = 0; i < 4; ++i) {
            const int q  = (wave * 4 + i) * 64 + lane;  // float-quad id 0..1023
            const int p  = (q & 7) * 4;
            const int b  = (q >> 3) & 15;
            const int tl = q >> 7;
            const float* g = src + ((size_t)((T0 + tl) * 16 + b)) * 4096 + p0 + p;
            glds16(g, (char*)ldsf + (size_t)(wave * 4 + i) * 1024);
        }
        __syncthreads();                     // drains vmcnt

        // ---- recurrence: 8 t-steps, 2 chains per thread
        #pragma unroll
        for (int tl = 0; tl < 8; ++tl) {
            const float x0 = ldsf[tl * 512 + bA * 32 + pA];
            const float x1 = ldsf[tl * 512 + (bA + 8) * 32 + pA];
            if (isA) {
                st0 = 0.5f * st0 + x0; c0 += x0 * st0;   // po update, then o*po
                st1 = 0.5f * st1 + x1; c1 += x1 * st1;
                ot[(tl * 16 + bA)     * 34 + pA] = f2bf(x0);
                ot[(tl * 16 + bA + 8) * 34 + pA] = f2bf(x1);
            } else {
                st0 = fminf(fmaxf(0.5f * st0 + x0, 0.f), 1.f);
                st1 = fminf(fmaxf(0.5f * st1 + x1, 0.f), 1.f);
                ot[(tl * 16 + bA)     * 34 + pA] = f2bf(st0);
                ot[(tl * 16 + bA + 8) * 34 + pA] = f2bf(st1);
            }
        }
        __syncthreads();

        // ---- flush: 128 contiguous k per p-row, 16-B vector stores
        const int pf = tid >> 3;             // 0..31
        const int c8 = tid & 7;
        #pragma unroll
        for (int i = 0; i < 2; ++i) {
            const int ch = c8 + i * 8;       // 16-B chunk 0..15
            ushort8 v;
            #pragma unroll
            for (int s = 0; s < 8; ++s) v[s] = ot[(ch * 8 + s) * 34 + pf];
            *(ushort8*)&dst[(size_t)(p0 + pf) * K_TOT + T0 * 16 + ch * 8] = v;
        }
    }

    if (isA) {
        cbuf[bA][pA] = c0 + c1;              // partial over b in {bA, bA+8}
        __syncthreads();
        if (tid < 32) {
            float s = 0.f;
            #pragma unroll
            for (int r = 0; r < 8; ++r) s += cbuf[r][tid];
            coef[p0 + tid] = s;
        }
    }
}

// ---------------------------------------------------------------------------
// 8-phase GEMM (see header ledger).
#define NTILES 16

// LDS region offsets (bytes): buf*65536 + isB*32768 + kh*16384 + row*64 + chunk*16
#define LOFF(buf, isB, kh) ((buf) * 65536 + (isB) * 32768 + (kh) * 16384)

__global__ __launch_bounds__(512, 2) void stdp_gemm_mfma(
        const unsigned short* __restrict__ AT,   // [POST][K] bf16 bits
        const unsigned short* __restrict__ BT,   // [PRE][K]  bf16 bits
        const float* __restrict__ W,             // [POST][PRE]
        const float* __restrict__ coef,          // [POST]
        float* __restrict__ Cout) {              // [POST][PRE]
    __shared__ __align__(16) char ldsraw[131072];   // 128 KB -> 1 block/CU

    const int tid  = threadIdx.x;
    const int lane = tid & 63;
    const int wave = tid >> 6;

    // XCD-bijective swizzle: 256 blocks = 8 XCD x 32; each XCD: 2 m-panels x 16 n.
    const int bid = blockIdx.x;
    const int f   = (bid & 7) * 32 + (bid >> 3);
    const int m0  = (f >> 4) * 256;
    const int n0  = (f & 15) * 256;

    const int wm  = (wave >> 2) * 128;           // 2 M-groups (rows within tile)
    const int wn  = (wave & 3) * 64;             // 4 N-groups
    const int rml = lane & 15;                   // fragment row within 16
    const int q   = lane >> 4;                   // k-chunk 0..3 within 32-k half
    const int swz16 = ((q ^ ((rml >> 1) & 3)) << 4);  // swizzled chunk byte offset

    floatx4 acc[8][4];
    #pragma unroll
    for (int i = 0; i < 8; ++i)
        #pragma unroll
        for (int j = 0; j < 4; ++j)
            acc[i][j] = (floatx4){0.f, 0.f, 0.f, 0.f};
    bf16x8 bv[4];                                // B-frags, live across phase pairs

    // Staging map: chunkID cid = j*512 + wave*64 + lane; row = cid>>2 (j=0: 0..127,
    // j=1: +128), slot = cid&3; slot receives global chunk slot^((row>>1)&3).
    // j=1 shares g (128>>1 = 64, 64&3 = 0) -> src1 = src0 + 128 rows.
    const int cid0 = wave * 64 + lane;
    const int row0 = cid0 >> 2;
    const int g0   = (cid0 & 3) ^ ((row0 >> 1) & 3);
    const unsigned short* gA0 = AT + (size_t)(m0 + row0) * K_TOT + g0 * 8;
    const unsigned short* gB0 = BT + (size_t)(n0 + row0) * K_TOT + g0 * 8;

    // stage one half-tile: matrix isB, K-tile t, k-half kh -> buf t&1
    #define STG(isB, t, kh)                                                        \
        do {                                                                       \
            const unsigned short* s0_ = ((isB) ? gB0 : gA0) + (t) * 64 + (kh) * 32;\
            char* d_ = ldsraw + LOFF((t) & 1, (isB), (kh)) + wave * 1024;          \
            glds16(s0_, d_);                                                       \
            glds16(s0_ + (size_t)128 * K_TOT, d_ + 8192);                          \
        } while (0)

    // one phase: compute quad (bufc, khc, mqc); optionally stage; wait mode WM
    // WM: 0 = none, 1 = vmcnt(4), 2 = vmcnt(0)
    #define PHASE(bufc, khc, mqc, SISB, ST, SKH, SCOND, WM)                        \
        do {                                                                       \
            const char* Ab_ = ldsraw + LOFF(bufc, 0, khc);                         \
            const char* Bb_ = ldsraw + LOFF(bufc, 1, khc);                         \
            if ((mqc) == 0) {                                                      \
                _Pragma("unroll")                                                  \
                for (int ni = 0; ni < 4; ++ni)                                     \
                    bv[ni] = *(const bf16x8*)(Bb_ + (wn + ni * 16 + rml) * 64 + swz16); \
            }                                                                      \
            bf16x8 af_[4];                                                         \
            _Pragma("unroll")                                                      \
            for (int k4 = 0; k4 < 4; ++k4)                                         \
                af_[k4] = *(const bf16x8*)(Ab_ + (wm + (mqc) * 64 + k4 * 16 + rml) * 64 + swz16); \
            if (SCOND) STG(SISB, ST, SKH);                                         \
            if ((WM) == 1)      asm volatile("s_waitcnt vmcnt(4)" ::: "memory");   \
            else if ((WM) == 2) asm volatile("s_waitcnt vmcnt(0)" ::: "memory");   \
            __builtin_amdgcn_s_barrier();                                          \
            __builtin_amdgcn_sched_barrier(0);                                     \
            __builtin_amdgcn_s_setprio(1);                                         \
            _Pragma("unroll")                                                      \
            for (int k4 = 0; k4 < 4; ++k4)                                         \
                _Pragma("unroll")                                                  \
                for (int ni = 0; ni < 4; ++ni)                                     \
                    acc[(mqc) * 4 + k4][ni] = __builtin_amdgcn_mfma_f32_16x16x32_bf16( \
                        af_[k4], bv[ni], acc[(mqc) * 4 + k4][ni], 0, 0, 0);        \
            __builtin_amdgcn_s_setprio(0);                                         \
            __builtin_amdgcn_s_barrier();                                          \
            __builtin_amdgcn_sched_barrier(0);                                     \
        } while (0)

    // Prologue: stage tiles 0 and 1 (16 glds); vmcnt(8) -> tile 0 resident.
    STG(0, 0, 0); STG(1, 0, 0); STG(0, 0, 1); STG(1, 0, 1);
    STG(0, 1, 0); STG(1, 1, 0); STG(0, 1, 1); STG(1, 1, 1);
    asm volatile("s_waitcnt vmcnt(8)" ::: "memory");
    __builtin_amdgcn_s_barrier();
    __builtin_amdgcn_sched_barrier(0);

    for (int i = 0; i < 8; ++i) {
        const int t2 = 2 * i + 2, t3 = 2 * i + 3, tA = 2 * i + 1;
        const int wm4 = (i < 7) ? 1 : 2;         // ph4 wait: publish buf1
        const int wm8 = (i < 7) ? 1 : 0;         // ph8 wait: publish buf0 (none at end)
        PHASE(0, 0, 0, 0, tA, 1, i > 0,      0);     // ph1
        PHASE(0, 0, 1, 1, tA, 1, i > 0,      0);     // ph2
        PHASE(0, 1, 0, 0, t2, 0, t2 < NTILES, 0);    // ph3
        PHASE(0, 1, 1, 1, t2, 0, t2 < NTILES, wm4);  // ph4
        PHASE(1, 0, 0, 0, t2, 1, t2 < NTILES, 0);    // ph5
        PHASE(1, 0, 1, 1, t2, 1, t2 < NTILES, 0);    // ph6
        PHASE(1, 1, 0, 0, t3, 0, t3 < NTILES, 0);    // ph7
        PHASE(1, 1, 1, 1, t3, 0, t3 < NTILES, wm8);  // ph8
    }

    // Epilogue: C = acc - coef[o]*W. C/D layout: col=lane&15, row=quad*4+reg.
    const int colp = n0 + wn + rml;
    const int q4   = lane >> 4;
    #pragma unroll
    for (int mi = 0; mi < 8; ++mi) {
        #pragma unroll
        for (int r = 0; r < 4; ++r) {
            const int o = m0 + wm + mi * 16 + q4 * 4 + r;
            const float cf = coef[o];
            const float* wrow = &W[(size_t)o * PRE + colp];
            float* crow = &Cout[(size_t)o * PRE + colp];
            #pragma unroll
            for (int ni = 0; ni < 4; ++ni)
                crow[ni * 16] = acc[mi][ni][r] - cf * wrow[ni * 16];
        }
    }
    #undef PHASE
    #undef STG
}

// ---------------------------------------------------------------------------
extern "C" void kernel_launch(void* const* d_in, const int* in_sizes, int n_in,
                              void* d_out, int out_size, void* d_ws, size_t ws_size,
                              hipStream_t stream) {
    const float* in_spikes  = (const float*)d_in[0];
    const float* out_spikes = (const float*)d_in[1];
    const float* weight     = (const float*)d_in[2];
    float* out = (float*)d_out;

    unsigned short* AT = (unsigned short*)d_ws;                 // 8 MB
    unsigned short* BT = AT + (size_t)POST * K_TOT;             // 8 MB
    float* coef = (float*)(BT + (size_t)PRE * K_TOT);           // 16 KB

    trace_convert<<<256, 256, 0, stream>>>(in_spikes, out_spikes, AT, BT, coef);

    stdp_gemm_mfma<<<256, 512, 0, stream>>>(AT, BT, weight, coef, out);
}